// Round 4
// baseline (116.638 us; speedup 1.0000x reference)
//
#include <hip/hip_runtime.h>

#define NROWS 8192
#define NCENT 4096
#define DIM   256

#define AS1 __attribute__((address_space(1)))
#define AS3 __attribute__((address_space(3)))

typedef short bf16x8 __attribute__((ext_vector_type(8)));
typedef float f32x4  __attribute__((ext_vector_type(4)));

// fp32 -> bf16 round-to-nearest-even
__device__ inline unsigned short f2bf(float f) {
    unsigned u = __float_as_uint(f);
    return (unsigned short)((u + 0x7fffu + ((u >> 16) & 1u)) >> 16);
}

// ---------------------------------------------------------------------------
// Prepass: fp32 -> bf16 convert (row-major, unswizzled) + row norms.
// ws layout: norms[12288] | xbf[8192*256] | cbf[4096*256] | part[64*8192]
// ---------------------------------------------------------------------------
__global__ __launch_bounds__(256) void prep_kernel(const float* __restrict__ x,
                                                   const float* __restrict__ c,
                                                   float* __restrict__ norms,
                                                   unsigned short* __restrict__ xbf,
                                                   unsigned short* __restrict__ cbf) {
    const int t = threadIdx.x, lane = t & 63;
    const int wbase = (blockIdx.x * 4 + (t >> 6)) * 4;
    #pragma unroll
    for (int rr = 0; rr < 4; ++rr) {
        const int gw = wbase + rr;                        // 0..12287
        const float* src;
        unsigned short* dst;
        if (gw < NROWS) { src = x + (size_t)gw * DIM;           dst = xbf + (size_t)gw * DIM; }
        else            { src = c + (size_t)(gw - NROWS) * DIM; dst = cbf + (size_t)(gw - NROWS) * DIM; }
        float4 v = ((const float4*)src)[lane];
        ushort4 b;
        b.x = f2bf(v.x); b.y = f2bf(v.y); b.z = f2bf(v.z); b.w = f2bf(v.w);
        ((ushort4*)dst)[lane] = b;
        float s = v.x * v.x + v.y * v.y + v.z * v.z + v.w * v.w;
        #pragma unroll
        for (int m = 32; m; m >>= 1) s += __shfl_xor(s, m);
        if (lane == 0) norms[gw] = s;
    }
}

// ---------------------------------------------------------------------------
// Main kernel: 256x256 tile, BK=32, 8 waves (2Mx4N), per-wave 128x64 output.
// 4-slot LDS ring (128 KB), DEPTH-3 prefetch with counted vmcnt:
//   region t: s_waitcnt vmcnt(8)  [region t's 4 loads done; t+1,t+2 in flight]
//             s_barrier            [all waves passed their own vmcnt -> whole
//                                   tile t resident; slot (t-1)&3 reads done]
//             STAGE(slot (t+3)&3)  [safe WAR: overwrites the slot read in t-1]
//             12x ds_read_b128 + 32 MFMA (setprio 1)
// vmcnt never drains to 0 until the tail; loads get ~3 regions (>1200 cy) to
// land, covering L3/HBM latency. ONE barrier per region.
// LDS row = 32 bf16 = 64 B = 4 chunks of 16 B; physical chunk p at row r
// holds logical chunk p ^ ((r>>1)&3) -> frag ds_read_b128 is 2-way bank
// aliasing (free, m136). Swizzle via per-lane staging SOURCE address
// (global_load_lds dest is forced lane-contiguous, m104/m108).
// Epilogue: NO atomics — per-wave partial row sums to part[slice][8192],
// slice = 4*col_block + wx; reduce_kernel sums 64 slices.
// ---------------------------------------------------------------------------
#define SLOT (256 * 32)   // shorts per matrix per ring slot (16 KB)

__global__ __launch_bounds__(512, 2) void rbf_mfma256(const unsigned short* __restrict__ xbf,
                                                      const unsigned short* __restrict__ cbf,
                                                      const float* __restrict__ w,
                                                      const float* __restrict__ sigp,
                                                      const float* __restrict__ norms,
                                                      float* __restrict__ part) {
    __shared__ __align__(16) short As[4 * SLOT];   // 64 KB
    __shared__ __align__(16) short Bs[4 * SLOT];   // 64 KB

    const int t    = threadIdx.x;
    const int wave = t >> 6, lane = t & 63;

    // XCD-chunked bijective swizzle over 512 blocks (32 row x 16 col tiles)
    const int bid = blockIdx.x;
    const int swz = (bid & 7) * 64 + (bid >> 3);
    const int m0  = (swz >> 4) * 256;
    const int n0  = (swz & 15) * 256;

    const int wy = wave >> 2, wx = wave & 3;   // 2x4 wave grid
    const int lr = lane & 15;                  // frag m/n index
    const int g  = lane >> 4;                  // frag k-group

    // ---- staging: wave stages rows 32w..32w+31 of A and B (2 loads each) ----
    const int r_in = lane >> 2;                        // 0..15 (16 rows/load)
    const int c_l  = (lane & 3) ^ ((r_in >> 1) & 3);   // logical chunk to fetch
    const unsigned short* ga0 = xbf + (size_t)(m0 + 32 * wave + r_in) * DIM + c_l * 8;
    const unsigned short* ga1 = ga0 + 16 * DIM;
    const unsigned short* gb0 = cbf + (size_t)(n0 + 32 * wave + r_in) * DIM + c_l * 8;
    const unsigned short* gb1 = gb0 + 16 * DIM;
    short* la0 = As + (32 * wave) * 32;                // uniform dest base per wave
    short* lb0 = Bs + (32 * wave) * 32;

#define STAGE(s, kk) do {                                                                   \
        const int ko_ = (kk) * 32;                                                          \
        __builtin_amdgcn_global_load_lds((const AS1 void*)(ga0 + ko_),                      \
                                         (AS3 void*)(la0 + (s) * SLOT), 16, 0, 0);          \
        __builtin_amdgcn_global_load_lds((const AS1 void*)(ga1 + ko_),                      \
                                         (AS3 void*)(la0 + (s) * SLOT + 16 * 32), 16, 0, 0);\
        __builtin_amdgcn_global_load_lds((const AS1 void*)(gb0 + ko_),                      \
                                         (AS3 void*)(lb0 + (s) * SLOT), 16, 0, 0);          \
        __builtin_amdgcn_global_load_lds((const AS1 void*)(gb1 + ko_),                      \
                                         (AS3 void*)(lb0 + (s) * SLOT + 16 * 32), 16, 0, 0);\
    } while (0)

    // ---- fragment read offsets (shorts) ----
    int aoff[8], boff[4];
    #pragma unroll
    for (int i = 0; i < 8; ++i) {
        int r = 128 * wy + 16 * i + lr;
        aoff[i] = r * 32 + ((g ^ ((r >> 1) & 3)) * 8);
    }
    #pragma unroll
    for (int j = 0; j < 4; ++j) {
        int r = 64 * wx + 16 * j + lr;
        boff[j] = r * 32 + ((g ^ ((r >> 1) & 3)) * 8);
    }

    f32x4 acc[8][4];
    #pragma unroll
    for (int i = 0; i < 8; ++i)
        #pragma unroll
        for (int j = 0; j < 4; ++j) acc[i][j] = f32x4{0, 0, 0, 0};

    // ---- prologue: issue regions 0,1,2 (12 loads in flight) ----
    STAGE(0, 0);
    STAGE(1, 1);
    STAGE(2, 2);
    __builtin_amdgcn_sched_barrier(0);

    #pragma unroll
    for (int kt = 0; kt < 8; ++kt) {
        // wait for region kt's 4 loads only; later regions stay in flight
        if (kt <= 5)      asm volatile("s_waitcnt vmcnt(8)" ::: "memory");
        else if (kt == 6) asm volatile("s_waitcnt vmcnt(4)" ::: "memory");
        else              asm volatile("s_waitcnt vmcnt(0)" ::: "memory");
        __builtin_amdgcn_s_barrier();          // all waves: kt data ready, kt-1 reads done
        __builtin_amdgcn_sched_barrier(0);

        if (kt <= 4) STAGE((kt + 3) & 3, kt + 3);   // overwrite slot read in region kt-1
        __builtin_amdgcn_sched_barrier(0);          // pin issue before compute cluster

        const short* Ab = As + (kt & 3) * SLOT;
        const short* Bb = Bs + (kt & 3) * SLOT;
        bf16x8 a[8], b[4];
        #pragma unroll
        for (int i = 0; i < 8; ++i) a[i] = *(const bf16x8*)(Ab + aoff[i]);
        #pragma unroll
        for (int j = 0; j < 4; ++j) b[j] = *(const bf16x8*)(Bb + boff[j]);
        __builtin_amdgcn_s_setprio(1);
        #pragma unroll
        for (int i = 0; i < 8; ++i)
            #pragma unroll
            for (int j = 0; j < 4; ++j)
                acc[i][j] = __builtin_amdgcn_mfma_f32_16x16x32_bf16(a[i], b[j], acc[i][j], 0, 0, 0);
        __builtin_amdgcn_s_setprio(0);
    }
#undef STAGE

    // ---- epilogue: phi = w*exp(-sigma*max(d2,0)); NO atomics ----
    const float sigma = sigp[0];
    const float* x2 = norms;
    const float* c2 = norms + NROWS;
    const int sl = (n0 >> 8) * 4 + wx;         // partial slice 0..63

    float c2v[4], wv[4];
    #pragma unroll
    for (int j = 0; j < 4; ++j) {
        int n = n0 + 64 * wx + 16 * j + lr;
        c2v[j] = c2[n];
        wv[j]  = w[n];
    }

    #pragma unroll
    for (int i = 0; i < 8; ++i) {
        const int mbase = m0 + 128 * wy + 16 * i + 4 * g;   // 4 consecutive rows
        float4 x2v = *(const float4*)(x2 + mbase);
        float rs[4] = {0.f, 0.f, 0.f, 0.f};
        #pragma unroll
        for (int j = 0; j < 4; ++j) {
            #pragma unroll
            for (int r = 0; r < 4; ++r) {
                float x2r = (r == 0) ? x2v.x : (r == 1) ? x2v.y : (r == 2) ? x2v.z : x2v.w;
                float d2 = x2r + c2v[j] - 2.0f * acc[i][j][r];
                d2 = fmaxf(d2, 0.0f);
                rs[r] += wv[j] * __expf(-sigma * d2);
            }
        }
        #pragma unroll
        for (int r = 0; r < 4; ++r) {
            rs[r] += __shfl_xor(rs[r], 1);
            rs[r] += __shfl_xor(rs[r], 2);
            rs[r] += __shfl_xor(rs[r], 4);
            rs[r] += __shfl_xor(rs[r], 8);
        }
        if (lr == 0) {
            float4 v = make_float4(rs[0], rs[1], rs[2], rs[3]);
            *(float4*)(part + (size_t)sl * NROWS + mbase) = v;
        }
    }
}

// ---------------------------------------------------------------------------
// Reduce: out[m] = sum over 64 partial slices. Fully writes out (no memset).
// ---------------------------------------------------------------------------
__global__ __launch_bounds__(256) void reduce_kernel(const float* __restrict__ part,
                                                     float* __restrict__ out) {
    const int m = blockIdx.x * 256 + threadIdx.x;
    float s = 0.f;
    #pragma unroll
    for (int p = 0; p < 64; ++p) s += part[(size_t)p * NROWS + m];
    out[m] = s;
}

// ---------------------------------------------------------------------------
// Fallback (R2 kernels) if ws is too small for the scratch buffers.
// ---------------------------------------------------------------------------
__global__ __launch_bounds__(256) void norms_kernel(const float* __restrict__ x,
                                                    const float* __restrict__ c,
                                                    float* __restrict__ ws) {
    int t = threadIdx.x, lane = t & 63;
    int gw = blockIdx.x * 4 + (t >> 6);
    const float* src;
    float* dst;
    if (gw < NROWS) { src = x + (size_t)gw * DIM;           dst = ws + gw; }
    else            { src = c + (size_t)(gw - NROWS) * DIM; dst = ws + gw; }
    float4 v = ((const float4*)src)[lane];
    float s = v.x * v.x + v.y * v.y + v.z * v.z + v.w * v.w;
    #pragma unroll
    for (int m = 32; m; m >>= 1) s += __shfl_xor(s, m);
    if (lane == 0) *dst = s;
}

__global__ __launch_bounds__(256) void rbf_kernel(const float* __restrict__ x,
                                                  const float* __restrict__ cent,
                                                  const float* __restrict__ w,
                                                  const float* __restrict__ sigp,
                                                  const float* __restrict__ norms,
                                                  float* __restrict__ out) {
    __shared__ __align__(16) short xs[64 * 32];
    __shared__ __align__(16) short cs[64 * 32];
    const int t = threadIdx.x;
    const int m0 = blockIdx.y * 64, n0 = blockIdx.x * 64;
    const int srow = t >> 2, seg = t & 3;
    const int pchunk = seg ^ ((srow >> 1) & 3);
    const int sidx = srow * 32 + pchunk * 8;
    const float* xg = x    + (size_t)(m0 + srow) * DIM + seg * 8;
    const float* cg = cent + (size_t)(n0 + srow) * DIM + seg * 8;
    const int lane = t & 63, wave = t >> 6;
    const int lr = lane & 15, lg = lane >> 4;
    const int arow = 16 * wave + lr;
    const int aidx = arow * 32 + ((lg ^ ((arow >> 1) & 3)) * 8);
    f32x4 acc[4] = {f32x4{0,0,0,0}, f32x4{0,0,0,0}, f32x4{0,0,0,0}, f32x4{0,0,0,0}};
    for (int k0 = 0; k0 < DIM; k0 += 32) {
        float4 f0 = *(const float4*)(xg + k0);
        float4 f1 = *(const float4*)(xg + k0 + 4);
        float4 g0 = *(const float4*)(cg + k0);
        float4 g1 = *(const float4*)(cg + k0 + 4);
        __syncthreads();
        union { unsigned short s[8]; int4 v; } ux, uc;
        ux.s[0]=f2bf(f0.x); ux.s[1]=f2bf(f0.y); ux.s[2]=f2bf(f0.z); ux.s[3]=f2bf(f0.w);
        ux.s[4]=f2bf(f1.x); ux.s[5]=f2bf(f1.y); ux.s[6]=f2bf(f1.z); ux.s[7]=f2bf(f1.w);
        uc.s[0]=f2bf(g0.x); uc.s[1]=f2bf(g0.y); uc.s[2]=f2bf(g0.z); uc.s[3]=f2bf(g0.w);
        uc.s[4]=f2bf(g1.x); uc.s[5]=f2bf(g1.y); uc.s[6]=f2bf(g1.z); uc.s[7]=f2bf(g1.w);
        *(int4*)(xs + sidx) = ux.v;
        *(int4*)(cs + sidx) = uc.v;
        __syncthreads();
        bf16x8 a = *(const bf16x8*)(xs + aidx);
        #pragma unroll
        for (int bt = 0; bt < 4; ++bt) {
            const int brow = 16 * bt + lr;
            bf16x8 b = *(const bf16x8*)(cs + brow * 32 + ((lg ^ ((brow >> 1) & 3)) * 8));
            acc[bt] = __builtin_amdgcn_mfma_f32_16x16x32_bf16(a, b, acc[bt], 0, 0, 0);
        }
    }
    const float sigma = sigp[0];
    const float* x2 = norms;
    const float* c2 = norms + NROWS;
    const int rbase = m0 + 16 * wave + lg * 4;
    float x2v[4];
    #pragma unroll
    for (int r = 0; r < 4; ++r) x2v[r] = x2[rbase + r];
    float rs[4] = {0.f, 0.f, 0.f, 0.f};
    #pragma unroll
    for (int bt = 0; bt < 4; ++bt) {
        const int col = n0 + 16 * bt + lr;
        const float c2v = c2[col];
        const float wvv = w[col];
        #pragma unroll
        for (int r = 0; r < 4; ++r) {
            float d2 = x2v[r] + c2v - 2.0f * acc[bt][r];
            d2 = fmaxf(d2, 0.0f);
            rs[r] += wvv * __expf(-sigma * d2);
        }
    }
    #pragma unroll
    for (int r = 0; r < 4; ++r) {
        rs[r] += __shfl_xor(rs[r], 1);
        rs[r] += __shfl_xor(rs[r], 2);
        rs[r] += __shfl_xor(rs[r], 4);
        rs[r] += __shfl_xor(rs[r], 8);
    }
    if (lr == 0) {
        #pragma unroll
        for (int r = 0; r < 4; ++r) atomicAdd(&out[rbase + r], rs[r]);
    }
}

extern "C" void kernel_launch(void* const* d_in, const int* in_sizes, int n_in,
                              void* d_out, int out_size, void* d_ws, size_t ws_size,
                              hipStream_t stream) {
    const float* x    = (const float*)d_in[0];
    const float* cent = (const float*)d_in[1];
    const float* w    = (const float*)d_in[2];
    const float* sig  = (const float*)d_in[3];
    float* out = (float*)d_out;

    const size_t norms_elems = NROWS + NCENT;              // 12288 floats
    const size_t xbf_off  = norms_elems * sizeof(float);   // 48 KB
    const size_t cbf_off  = xbf_off + (size_t)NROWS * DIM * sizeof(unsigned short);
    const size_t part_off = cbf_off + (size_t)NCENT * DIM * sizeof(unsigned short);
    const size_t ws_need  = part_off + (size_t)64 * NROWS * sizeof(float);

    if (ws_size >= ws_need) {
        float* norms = (float*)d_ws;
        unsigned short* xbf = (unsigned short*)((char*)d_ws + xbf_off);
        unsigned short* cbf = (unsigned short*)((char*)d_ws + cbf_off);
        float* part = (float*)((char*)d_ws + part_off);
        prep_kernel<<<(NROWS + NCENT) / 16, 256, 0, stream>>>(x, cent, norms, xbf, cbf);
        rbf_mfma256<<<512, 512, 0, stream>>>(xbf, cbf, w, sig, norms, part);
        reduce_kernel<<<NROWS / 256, 256, 0, stream>>>(part, out);
    } else {
        float* norms = (float*)d_ws;
        hipMemsetAsync(d_out, 0, (size_t)out_size * sizeof(float), stream);
        norms_kernel<<<(NROWS + NCENT) / 4, 256, 0, stream>>>(x, cent, norms);
        rbf_kernel<<<dim3(NCENT / 64, NROWS / 64), 256, 0, stream>>>(x, cent, w, sig, norms, out);
    }
}

// Round 5
// 115.572 us; speedup vs baseline: 1.0092x; 1.0092x over previous
//
#include <hip/hip_runtime.h>

#define NROWS 8192
#define NCENT 4096
#define DIM   256

#define AS1 __attribute__((address_space(1)))
#define AS3 __attribute__((address_space(3)))

typedef short bf16x8 __attribute__((ext_vector_type(8)));
typedef float f32x4  __attribute__((ext_vector_type(4)));

// fp32 -> bf16 round-to-nearest-even
__device__ inline unsigned short f2bf(float f) {
    unsigned u = __float_as_uint(f);
    return (unsigned short)((u + 0x7fffu + ((u >> 16) & 1u)) >> 16);
}

// ---------------------------------------------------------------------------
// Prepass: fp32 -> bf16 convert (row-major, unswizzled) + row norms.
// ws layout: norms[12288] | xbf[8192*256] | cbf[4096*256] | part[64*8192]
// ---------------------------------------------------------------------------
__global__ __launch_bounds__(256) void prep_kernel(const float* __restrict__ x,
                                                   const float* __restrict__ c,
                                                   float* __restrict__ norms,
                                                   unsigned short* __restrict__ xbf,
                                                   unsigned short* __restrict__ cbf) {
    const int t = threadIdx.x, lane = t & 63;
    const int wbase = (blockIdx.x * 4 + (t >> 6)) * 4;
    #pragma unroll
    for (int rr = 0; rr < 4; ++rr) {
        const int gw = wbase + rr;                        // 0..12287
        const float* src;
        unsigned short* dst;
        if (gw < NROWS) { src = x + (size_t)gw * DIM;           dst = xbf + (size_t)gw * DIM; }
        else            { src = c + (size_t)(gw - NROWS) * DIM; dst = cbf + (size_t)(gw - NROWS) * DIM; }
        float4 v = ((const float4*)src)[lane];
        ushort4 b;
        b.x = f2bf(v.x); b.y = f2bf(v.y); b.z = f2bf(v.z); b.w = f2bf(v.w);
        ((ushort4*)dst)[lane] = b;
        float s = v.x * v.x + v.y * v.y + v.z * v.z + v.w * v.w;
        #pragma unroll
        for (int m = 32; m; m >>= 1) s += __shfl_xor(s, m);
        if (lane == 0) norms[gw] = s;
    }
}

// ---------------------------------------------------------------------------
// Main kernel: 128x128 tile, BK=32, 4 waves (2Mx2N), per-wave 64x64 output.
// HIGH-TLP shape: 2048 blocks x 256 threads; LDS 48 KB (3-slot ring) +
// __launch_bounds__(256,3) -> 3 blocks/CU (12 waves/CU). Cross-block TLP
// covers barrier/prologue/epilogue stalls (m114: implicit overlap captures
// what source pipelining adds); this is what the 512x512 shape lacked.
// Depth-2 counted-vmcnt prefetch on a 3-slot ring:
//   region t: s_waitcnt vmcnt(4)  [t's 4 loads done; t+1's in flight]
//             s_barrier            [all waves: tile t resident, t-1 reads done]
//             STAGE(slot (t+2)%3)  [safe WAR: slot (t-1)%3, reads done at bar]
//             8x ds_read_b128 + 16 MFMA (setprio 1)
// vmcnt never drains to 0 until the tail.
// LDS row = 32 bf16 = 64 B = 4 chunks of 16 B; physical chunk p at row r
// holds logical chunk p ^ ((r>>1)&3) -> frag ds_read_b128 is 2-way bank
// aliasing (free, m136). Swizzle via per-lane staging SOURCE address
// (global_load_lds dest is forced lane-contiguous, m104/m108).
// Grid: XCD-chunked swizzle (2048%8==0): xcd = bid&7 gets 8 contiguous
// M-stripes x all 32 N-tiles = A 512KB + B 2MB = 2.5MB < 4MB per-XCD L2.
// Epilogue: NO atomics — per-wave partial row sums to part[slice][8192],
// slice = 2*n_tile + wx; reduce_kernel sums 64 slices.
// ---------------------------------------------------------------------------
#define SLOT (128 * 32)   // shorts per matrix per ring slot (8 KB)

__global__ __launch_bounds__(256, 3) void rbf_mfma128(const unsigned short* __restrict__ xbf,
                                                      const unsigned short* __restrict__ cbf,
                                                      const float* __restrict__ w,
                                                      const float* __restrict__ sigp,
                                                      const float* __restrict__ norms,
                                                      float* __restrict__ part) {
    __shared__ __align__(16) short As[3 * SLOT];   // 24 KB
    __shared__ __align__(16) short Bs[3 * SLOT];   // 24 KB

    const int t    = threadIdx.x;
    const int wave = t >> 6, lane = t & 63;

    // XCD-chunked bijective swizzle: tid = (bid&7)*256 + bid>>3; 64 M x 32 N
    const int bid = blockIdx.x;
    const int tid = (bid & 7) * 256 + (bid >> 3);
    const int m0  = (tid >> 5) * 128;
    const int n0  = (tid & 31) * 128;

    const int wy = wave >> 1, wx = wave & 1;   // 2x2 wave grid
    const int lr = lane & 15;                  // frag m/n index
    const int g  = lane >> 4;                  // frag k-group

    // ---- staging: wave stages rows 32w..32w+31 of A and B (2 loads each) ----
    const int r_in = lane >> 2;                        // 0..15 (16 rows/load)
    const int c_l  = (lane & 3) ^ ((r_in >> 1) & 3);   // logical chunk to fetch
    const unsigned short* ga0 = xbf + (size_t)(m0 + 32 * wave + r_in) * DIM + c_l * 8;
    const unsigned short* ga1 = ga0 + 16 * DIM;
    const unsigned short* gb0 = cbf + (size_t)(n0 + 32 * wave + r_in) * DIM + c_l * 8;
    const unsigned short* gb1 = gb0 + 16 * DIM;
    short* la0 = As + (32 * wave) * 32;                // uniform dest base per wave
    short* lb0 = Bs + (32 * wave) * 32;

#define STAGE(s, kk) do {                                                                   \
        const int ko_ = (kk) * 32;                                                          \
        __builtin_amdgcn_global_load_lds((const AS1 void*)(ga0 + ko_),                      \
                                         (AS3 void*)(la0 + (s) * SLOT), 16, 0, 0);          \
        __builtin_amdgcn_global_load_lds((const AS1 void*)(ga1 + ko_),                      \
                                         (AS3 void*)(la0 + (s) * SLOT + 16 * 32), 16, 0, 0);\
        __builtin_amdgcn_global_load_lds((const AS1 void*)(gb0 + ko_),                      \
                                         (AS3 void*)(lb0 + (s) * SLOT), 16, 0, 0);          \
        __builtin_amdgcn_global_load_lds((const AS1 void*)(gb1 + ko_),                      \
                                         (AS3 void*)(lb0 + (s) * SLOT + 16 * 32), 16, 0, 0);\
    } while (0)

    // ---- fragment read offsets (shorts) ----
    int aoff[4], boff[4];
    #pragma unroll
    for (int i = 0; i < 4; ++i) {
        int r = 64 * wy + 16 * i + lr;
        aoff[i] = r * 32 + ((g ^ ((r >> 1) & 3)) * 8);
    }
    #pragma unroll
    for (int j = 0; j < 4; ++j) {
        int r = 64 * wx + 16 * j + lr;
        boff[j] = r * 32 + ((g ^ ((r >> 1) & 3)) * 8);
    }

    f32x4 acc[4][4];
    #pragma unroll
    for (int i = 0; i < 4; ++i)
        #pragma unroll
        for (int j = 0; j < 4; ++j) acc[i][j] = f32x4{0, 0, 0, 0};

    // ---- prologue: issue regions 0,1 (8 loads in flight) ----
    STAGE(0, 0);
    STAGE(1, 1);
    __builtin_amdgcn_sched_barrier(0);

    #pragma unroll
    for (int kt = 0; kt < 8; ++kt) {
        // wait for region kt's 4 loads only; region kt+1 stays in flight
        if (kt <= 6) asm volatile("s_waitcnt vmcnt(4)" ::: "memory");
        else         asm volatile("s_waitcnt vmcnt(0)" ::: "memory");
        __builtin_amdgcn_s_barrier();          // tile kt resident; kt-1 reads done
        __builtin_amdgcn_sched_barrier(0);

        if (kt <= 5) STAGE((kt + 2) % 3, kt + 2);   // overwrite slot read in kt-1
        __builtin_amdgcn_sched_barrier(0);          // pin issue before compute

        const short* Ab = As + (kt % 3) * SLOT;
        const short* Bb = Bs + (kt % 3) * SLOT;
        bf16x8 a[4], b[4];
        #pragma unroll
        for (int i = 0; i < 4; ++i) a[i] = *(const bf16x8*)(Ab + aoff[i]);
        #pragma unroll
        for (int j = 0; j < 4; ++j) b[j] = *(const bf16x8*)(Bb + boff[j]);
        __builtin_amdgcn_s_setprio(1);
        #pragma unroll
        for (int i = 0; i < 4; ++i)
            #pragma unroll
            for (int j = 0; j < 4; ++j)
                acc[i][j] = __builtin_amdgcn_mfma_f32_16x16x32_bf16(a[i], b[j], acc[i][j], 0, 0, 0);
        __builtin_amdgcn_s_setprio(0);
    }
#undef STAGE

    // ---- epilogue: phi = w*exp(-sigma*max(d2,0)); NO atomics ----
    const float sigma = sigp[0];
    const float* x2 = norms;
    const float* c2 = norms + NROWS;
    const int sl = (n0 >> 7) * 2 + wx;         // partial slice 0..63

    float c2v[4], wv[4];
    #pragma unroll
    for (int j = 0; j < 4; ++j) {
        int n = n0 + 64 * wx + 16 * j + lr;
        c2v[j] = c2[n];
        wv[j]  = w[n];
    }

    #pragma unroll
    for (int i = 0; i < 4; ++i) {
        const int mbase = m0 + 64 * wy + 16 * i + 4 * g;   // 4 consecutive rows
        float4 x2v = *(const float4*)(x2 + mbase);
        float rs[4] = {0.f, 0.f, 0.f, 0.f};
        #pragma unroll
        for (int j = 0; j < 4; ++j) {
            #pragma unroll
            for (int r = 0; r < 4; ++r) {
                float x2r = (r == 0) ? x2v.x : (r == 1) ? x2v.y : (r == 2) ? x2v.z : x2v.w;
                float d2 = x2r + c2v[j] - 2.0f * acc[i][j][r];
                d2 = fmaxf(d2, 0.0f);
                rs[r] += wv[j] * __expf(-sigma * d2);
            }
        }
        #pragma unroll
        for (int r = 0; r < 4; ++r) {
            rs[r] += __shfl_xor(rs[r], 1);
            rs[r] += __shfl_xor(rs[r], 2);
            rs[r] += __shfl_xor(rs[r], 4);
            rs[r] += __shfl_xor(rs[r], 8);
        }
        if (lr == 0) {
            float4 v = make_float4(rs[0], rs[1], rs[2], rs[3]);
            *(float4*)(part + (size_t)sl * NROWS + mbase) = v;
        }
    }
}

// ---------------------------------------------------------------------------
// Reduce: out[m] = sum over 64 partial slices. Fully writes out (no memset).
// ---------------------------------------------------------------------------
__global__ __launch_bounds__(256) void reduce_kernel(const float* __restrict__ part,
                                                     float* __restrict__ out) {
    const int m = blockIdx.x * 256 + threadIdx.x;
    float s = 0.f;
    #pragma unroll
    for (int p = 0; p < 64; ++p) s += part[(size_t)p * NROWS + m];
    out[m] = s;
}

// ---------------------------------------------------------------------------
// Fallback (R2 kernels) if ws is too small for the scratch buffers.
// ---------------------------------------------------------------------------
__global__ __launch_bounds__(256) void norms_kernel(const float* __restrict__ x,
                                                    const float* __restrict__ c,
                                                    float* __restrict__ ws) {
    int t = threadIdx.x, lane = t & 63;
    int gw = blockIdx.x * 4 + (t >> 6);
    const float* src;
    float* dst;
    if (gw < NROWS) { src = x + (size_t)gw * DIM;           dst = ws + gw; }
    else            { src = c + (size_t)(gw - NROWS) * DIM; dst = ws + gw; }
    float4 v = ((const float4*)src)[lane];
    float s = v.x * v.x + v.y * v.y + v.z * v.z + v.w * v.w;
    #pragma unroll
    for (int m = 32; m; m >>= 1) s += __shfl_xor(s, m);
    if (lane == 0) *dst = s;
}

__global__ __launch_bounds__(256) void rbf_kernel(const float* __restrict__ x,
                                                  const float* __restrict__ cent,
                                                  const float* __restrict__ w,
                                                  const float* __restrict__ sigp,
                                                  const float* __restrict__ norms,
                                                  float* __restrict__ out) {
    __shared__ __align__(16) short xs[64 * 32];
    __shared__ __align__(16) short cs[64 * 32];
    const int t = threadIdx.x;
    const int m0 = blockIdx.y * 64, n0 = blockIdx.x * 64;
    const int srow = t >> 2, seg = t & 3;
    const int pchunk = seg ^ ((srow >> 1) & 3);
    const int sidx = srow * 32 + pchunk * 8;
    const float* xg = x    + (size_t)(m0 + srow) * DIM + seg * 8;
    const float* cg = cent + (size_t)(n0 + srow) * DIM + seg * 8;
    const int lane = t & 63, wave = t >> 6;
    const int lr = lane & 15, lg = lane >> 4;
    const int arow = 16 * wave + lr;
    const int aidx = arow * 32 + ((lg ^ ((arow >> 1) & 3)) * 8);
    f32x4 acc[4] = {f32x4{0,0,0,0}, f32x4{0,0,0,0}, f32x4{0,0,0,0}, f32x4{0,0,0,0}};
    for (int k0 = 0; k0 < DIM; k0 += 32) {
        float4 f0 = *(const float4*)(xg + k0);
        float4 f1 = *(const float4*)(xg + k0 + 4);
        float4 g0 = *(const float4*)(cg + k0);
        float4 g1 = *(const float4*)(cg + k0 + 4);
        __syncthreads();
        union { unsigned short s[8]; int4 v; } ux, uc;
        ux.s[0]=f2bf(f0.x); ux.s[1]=f2bf(f0.y); ux.s[2]=f2bf(f0.z); ux.s[3]=f2bf(f0.w);
        ux.s[4]=f2bf(f1.x); ux.s[5]=f2bf(f1.y); ux.s[6]=f2bf(f1.z); ux.s[7]=f2bf(f1.w);
        uc.s[0]=f2bf(g0.x); uc.s[1]=f2bf(g0.y); uc.s[2]=f2bf(g0.z); uc.s[3]=f2bf(g0.w);
        uc.s[4]=f2bf(g1.x); uc.s[5]=f2bf(g1.y); uc.s[6]=f2bf(g1.z); uc.s[7]=f2bf(g1.w);
        *(int4*)(xs + sidx) = ux.v;
        *(int4*)(cs + sidx) = uc.v;
        __syncthreads();
        bf16x8 a = *(const bf16x8*)(xs + aidx);
        #pragma unroll
        for (int bt = 0; bt < 4; ++bt) {
            const int brow = 16 * bt + lr;
            bf16x8 b = *(const bf16x8*)(cs + brow * 32 + ((lg ^ ((brow >> 1) & 3)) * 8));
            acc[bt] = __builtin_amdgcn_mfma_f32_16x16x32_bf16(a, b, acc[bt], 0, 0, 0);
        }
    }
    const float sigma = sigp[0];
    const float* x2 = norms;
    const float* c2 = norms + NROWS;
    const int rbase = m0 + 16 * wave + lg * 4;
    float x2v[4];
    #pragma unroll
    for (int r = 0; r < 4; ++r) x2v[r] = x2[rbase + r];
    float rs[4] = {0.f, 0.f, 0.f, 0.f};
    #pragma unroll
    for (int bt = 0; bt < 4; ++bt) {
        const int col = n0 + 16 * bt + lr;
        const float c2v = c2[col];
        const float wvv = w[col];
        #pragma unroll
        for (int r = 0; r < 4; ++r) {
            float d2 = x2v[r] + c2v - 2.0f * acc[bt][r];
            d2 = fmaxf(d2, 0.0f);
            rs[r] += wvv * __expf(-sigma * d2);
        }
    }
    #pragma unroll
    for (int r = 0; r < 4; ++r) {
        rs[r] += __shfl_xor(rs[r], 1);
        rs[r] += __shfl_xor(rs[r], 2);
        rs[r] += __shfl_xor(rs[r], 4);
        rs[r] += __shfl_xor(rs[r], 8);
    }
    if (lr == 0) {
        #pragma unroll
        for (int r = 0; r < 4; ++r) atomicAdd(&out[rbase + r], rs[r]);
    }
}

extern "C" void kernel_launch(void* const* d_in, const int* in_sizes, int n_in,
                              void* d_out, int out_size, void* d_ws, size_t ws_size,
                              hipStream_t stream) {
    const float* x    = (const float*)d_in[0];
    const float* cent = (const float*)d_in[1];
    const float* w    = (const float*)d_in[2];
    const float* sig  = (const float*)d_in[3];
    float* out = (float*)d_out;

    const size_t norms_elems = NROWS + NCENT;              // 12288 floats
    const size_t xbf_off  = norms_elems * sizeof(float);   // 48 KB
    const size_t cbf_off  = xbf_off + (size_t)NROWS * DIM * sizeof(unsigned short);
    const size_t part_off = cbf_off + (size_t)NCENT * DIM * sizeof(unsigned short);
    const size_t ws_need  = part_off + (size_t)64 * NROWS * sizeof(float);

    if (ws_size >= ws_need) {
        float* norms = (float*)d_ws;
        unsigned short* xbf = (unsigned short*)((char*)d_ws + xbf_off);
        unsigned short* cbf = (unsigned short*)((char*)d_ws + cbf_off);
        float* part = (float*)((char*)d_ws + part_off);
        prep_kernel<<<(NROWS + NCENT) / 16, 256, 0, stream>>>(x, cent, norms, xbf, cbf);
        rbf_mfma128<<<2048, 256, 0, stream>>>(xbf, cbf, w, sig, norms, part);
        reduce_kernel<<<NROWS / 256, 256, 0, stream>>>(part, out);
    } else {
        float* norms = (float*)d_ws;
        hipMemsetAsync(d_out, 0, (size_t)out_size * sizeof(float), stream);
        norms_kernel<<<(NROWS + NCENT) / 4, 256, 0, stream>>>(x, cent, norms);
        rbf_kernel<<<dim3(NCENT / 64, NROWS / 64), 256, 0, stream>>>(x, cent, w, sig, norms, out);
    }
}

// Round 6
// 103.276 us; speedup vs baseline: 1.1294x; 1.1191x over previous
//
#include <hip/hip_runtime.h>

#define NROWS 8192
#define NCENT 4096
#define DIM   256

#define AS1 __attribute__((address_space(1)))
#define AS3 __attribute__((address_space(3)))

typedef short bf16x8 __attribute__((ext_vector_type(8)));
typedef float f32x4  __attribute__((ext_vector_type(4)));

// fp32 -> bf16 round-to-nearest-even
__device__ inline unsigned short f2bf(float f) {
    unsigned u = __float_as_uint(f);
    return (unsigned short)((u + 0x7fffu + ((u >> 16) & 1u)) >> 16);
}

// ---------------------------------------------------------------------------
// Prepass: fp32 -> bf16 convert (row-major, unswizzled) + row norms.
// Also zeroes out[] (blocks 0..31), replacing the separate memset dispatch.
// 4 waves/block, 4 rows/wave -> 16 rows/block, 768 blocks.
// ws layout: norms[12288] | xbf[8192*256] | cbf[4096*256]
// ---------------------------------------------------------------------------
__global__ __launch_bounds__(256) void prep_kernel(const float* __restrict__ x,
                                                   const float* __restrict__ c,
                                                   float* __restrict__ norms,
                                                   unsigned short* __restrict__ xbf,
                                                   unsigned short* __restrict__ cbf,
                                                   float* __restrict__ out) {
    const int t = threadIdx.x, lane = t & 63;
    if (blockIdx.x < NROWS / 256) out[blockIdx.x * 256 + t] = 0.0f;
    const int wbase = (blockIdx.x * 4 + (t >> 6)) * 4;   // first row of this wave
    #pragma unroll
    for (int rr = 0; rr < 4; ++rr) {
        const int gw = wbase + rr;                        // 0..12287
        const float* src;
        unsigned short* dst;
        if (gw < NROWS) { src = x + (size_t)gw * DIM;           dst = xbf + (size_t)gw * DIM; }
        else            { src = c + (size_t)(gw - NROWS) * DIM; dst = cbf + (size_t)(gw - NROWS) * DIM; }
        float4 v = ((const float4*)src)[lane];
        ushort4 b;
        b.x = f2bf(v.x); b.y = f2bf(v.y); b.z = f2bf(v.z); b.w = f2bf(v.w);
        ((ushort4*)dst)[lane] = b;
        float s = v.x * v.x + v.y * v.y + v.z * v.z + v.w * v.w;
        #pragma unroll
        for (int m = 32; m; m >>= 1) s += __shfl_xor(s, m);
        if (lane == 0) norms[gw] = s;
    }
}

// ---------------------------------------------------------------------------
// Main kernel: 128x128 block tile, BK=32, 4 waves in 2x2 wave grid,
// 4x4 MFMA (16x16x32 bf16) tiles per wave. global_load_lds width-16 staging.
// R0-proven structure with ONE change: cross-iteration double buffer with a
// SINGLE __syncthreads per K-iter:
//     STAGE(next buf, kt+1)   // issue loads
//     compute(cur buf)        // ds_read + 16 MFMA (~300 cy) hides load latency
//     __syncthreads()         // compiler drains vmcnt(0): loads mostly landed
// (R0 drained immediately after issue -> exposed L2 latency every iter, and
// used two barriers/iter. No inline asm, no setprio, no sched_barrier: the
// measured-regressive pieces from R1-R5 are all removed.)
// LDS logical layout: row-major [row][32 bf16], 64 B/row; chunk (16 B) at
// physical position p holds logical chunk p ^ ((row>>1)&3)  -> frag reads are
// 2-way bank aliasing (free, m136). Swizzle applied via staging SOURCE addr
// (global_load_lds dest is forced lane-contiguous, m104/m108).
// ---------------------------------------------------------------------------
#define BUFH (128 * 32)   // shorts per matrix per buffer (8 KB)

__global__ __launch_bounds__(256) void rbf_mfma(const unsigned short* __restrict__ xbf,
                                                const unsigned short* __restrict__ cbf,
                                                const float* __restrict__ w,
                                                const float* __restrict__ sigp,
                                                const float* __restrict__ norms,
                                                float* __restrict__ out) {
    __shared__ __align__(16) short As[2 * BUFH];   // 16 KB
    __shared__ __align__(16) short Bs[2 * BUFH];   // 16 KB

    const int t    = threadIdx.x;
    const int wave = t >> 6, lane = t & 63;
    const int m0   = blockIdx.y * 128;
    const int n0   = blockIdx.x * 128;
    const int wy   = wave >> 1, wx = wave & 1;
    const int lr   = lane & 15;       // frag m/n index
    const int g    = lane >> 4;       // frag k-group

    // ---- staging: wave stages rows 32w..32w+31 of both tiles (2 issues ea) ----
    const int r_in = lane >> 2;                        // 0..15 within 16-row group
    const int c_l  = (lane & 3) ^ ((r_in >> 1) & 3);   // logical chunk for this lane
    const unsigned short* ga0 = xbf + (size_t)(m0 + 32 * wave + r_in) * DIM + c_l * 8;
    const unsigned short* ga1 = ga0 + 16 * DIM;
    const unsigned short* gb0 = cbf + (size_t)(n0 + 32 * wave + r_in) * DIM + c_l * 8;
    const unsigned short* gb1 = gb0 + 16 * DIM;
    short* la0 = As + (32 * wave) * 32;                // uniform dest base per wave
    short* lb0 = Bs + (32 * wave) * 32;

#define STAGE(buf, kk) do {                                                                  \
        const int ko_ = (kk) * 32;                                                           \
        __builtin_amdgcn_global_load_lds((const AS1 void*)(ga0 + ko_),                       \
                                         (AS3 void*)(la0 + (buf) * BUFH), 16, 0, 0);         \
        __builtin_amdgcn_global_load_lds((const AS1 void*)(ga1 + ko_),                       \
                                         (AS3 void*)(la0 + (buf) * BUFH + 16 * 32), 16, 0, 0);\
        __builtin_amdgcn_global_load_lds((const AS1 void*)(gb0 + ko_),                       \
                                         (AS3 void*)(lb0 + (buf) * BUFH), 16, 0, 0);         \
        __builtin_amdgcn_global_load_lds((const AS1 void*)(gb1 + ko_),                       \
                                         (AS3 void*)(lb0 + (buf) * BUFH + 16 * 32), 16, 0, 0);\
    } while (0)

    // ---- fragment read offsets (shorts) ----
    int aoff[4], boff[4];
    #pragma unroll
    for (int i = 0; i < 4; ++i) {
        int r = 64 * wy + 16 * i + lr;
        aoff[i] = r * 32 + ((g ^ ((r >> 1) & 3)) * 8);
    }
    #pragma unroll
    for (int j = 0; j < 4; ++j) {
        int r = 64 * wx + 16 * j + lr;
        boff[j] = r * 32 + ((g ^ ((r >> 1) & 3)) * 8);
    }

    f32x4 acc[4][4];
    #pragma unroll
    for (int i = 0; i < 4; ++i)
        #pragma unroll
        for (int j = 0; j < 4; ++j) acc[i][j] = f32x4{0, 0, 0, 0};

    // ---- prologue: stage tile 0; single exposed drain ----
    STAGE(0, 0);
    __syncthreads();

    #pragma unroll
    for (int kk = 0; kk < DIM / 32; ++kk) {
        const int cur = kk & 1;
        if (kk < DIM / 32 - 1) STAGE(cur ^ 1, kk + 1);   // issue next; lands under compute

        const short* Ab = As + cur * BUFH;
        const short* Bb = Bs + cur * BUFH;
        bf16x8 a[4], b[4];
        #pragma unroll
        for (int i = 0; i < 4; ++i) a[i] = *(const bf16x8*)(Ab + aoff[i]);
        #pragma unroll
        for (int j = 0; j < 4; ++j) b[j] = *(const bf16x8*)(Bb + boff[j]);
        #pragma unroll
        for (int i = 0; i < 4; ++i)
            #pragma unroll
            for (int j = 0; j < 4; ++j)
                acc[i][j] = __builtin_amdgcn_mfma_f32_16x16x32_bf16(a[i], b[j], acc[i][j], 0, 0, 0);

        __syncthreads();   // drains next-tile loads (hidden by compute); WAR-safe
    }
#undef STAGE

    // ---- epilogue: phi = w*exp(-sigma*max(d2,0)); reduce 64 cols per row ----
    const float sigma = sigp[0];
    const float* x2 = norms;
    const float* c2 = norms + NROWS;

    float c2v[4], wv[4];
    #pragma unroll
    for (int j = 0; j < 4; ++j) {
        int n = n0 + 64 * wx + 16 * j + lr;
        c2v[j] = c2[n];
        wv[j]  = w[n];
    }

    #pragma unroll
    for (int i = 0; i < 4; ++i) {
        const int mbase = m0 + 64 * wy + 16 * i + 4 * g;   // 4 consecutive rows
        float4 x2v = *(const float4*)(x2 + mbase);
        float rs[4] = {0.f, 0.f, 0.f, 0.f};
        #pragma unroll
        for (int j = 0; j < 4; ++j) {
            #pragma unroll
            for (int r = 0; r < 4; ++r) {
                float x2r = (r == 0) ? x2v.x : (r == 1) ? x2v.y : (r == 2) ? x2v.z : x2v.w;
                float d2 = x2r + c2v[j] - 2.0f * acc[i][j][r];
                d2 = fmaxf(d2, 0.0f);
                rs[r] += wv[j] * __expf(-sigma * d2);
            }
        }
        #pragma unroll
        for (int r = 0; r < 4; ++r) {
            rs[r] += __shfl_xor(rs[r], 1);
            rs[r] += __shfl_xor(rs[r], 2);
            rs[r] += __shfl_xor(rs[r], 4);
            rs[r] += __shfl_xor(rs[r], 8);
        }
        if (lr == 0) {
            #pragma unroll
            for (int r = 0; r < 4; ++r) atomicAdd(&out[mbase + r], rs[r]);
        }
    }
}

// ---------------------------------------------------------------------------
// Fallback (R2 kernels) if ws is too small for the bf16 scratch copies.
// ---------------------------------------------------------------------------
__global__ __launch_bounds__(256) void norms_kernel(const float* __restrict__ x,
                                                    const float* __restrict__ c,
                                                    float* __restrict__ ws) {
    int t = threadIdx.x, lane = t & 63;
    int gw = blockIdx.x * 4 + (t >> 6);
    const float* src;
    float* dst;
    if (gw < NROWS) { src = x + (size_t)gw * DIM;           dst = ws + gw; }
    else            { src = c + (size_t)(gw - NROWS) * DIM; dst = ws + gw; }
    float4 v = ((const float4*)src)[lane];
    float s = v.x * v.x + v.y * v.y + v.z * v.z + v.w * v.w;
    #pragma unroll
    for (int m = 32; m; m >>= 1) s += __shfl_xor(s, m);
    if (lane == 0) *dst = s;
}

__global__ __launch_bounds__(256) void rbf_kernel(const float* __restrict__ x,
                                                  const float* __restrict__ cent,
                                                  const float* __restrict__ w,
                                                  const float* __restrict__ sigp,
                                                  const float* __restrict__ norms,
                                                  float* __restrict__ out) {
    __shared__ __align__(16) short xs[64 * 32];
    __shared__ __align__(16) short cs[64 * 32];
    const int t = threadIdx.x;
    const int m0 = blockIdx.y * 64, n0 = blockIdx.x * 64;
    const int srow = t >> 2, seg = t & 3;
    const int pchunk = seg ^ ((srow >> 1) & 3);
    const int sidx = srow * 32 + pchunk * 8;
    const float* xg = x    + (size_t)(m0 + srow) * DIM + seg * 8;
    const float* cg = cent + (size_t)(n0 + srow) * DIM + seg * 8;
    const int lane = t & 63, wave = t >> 6;
    const int lr = lane & 15, lg = lane >> 4;
    const int arow = 16 * wave + lr;
    const int aidx = arow * 32 + ((lg ^ ((arow >> 1) & 3)) * 8);
    f32x4 acc[4] = {f32x4{0,0,0,0}, f32x4{0,0,0,0}, f32x4{0,0,0,0}, f32x4{0,0,0,0}};
    for (int k0 = 0; k0 < DIM; k0 += 32) {
        float4 f0 = *(const float4*)(xg + k0);
        float4 f1 = *(const float4*)(xg + k0 + 4);
        float4 g0 = *(const float4*)(cg + k0);
        float4 g1 = *(const float4*)(cg + k0 + 4);
        __syncthreads();
        union { unsigned short s[8]; int4 v; } ux, uc;
        ux.s[0]=f2bf(f0.x); ux.s[1]=f2bf(f0.y); ux.s[2]=f2bf(f0.z); ux.s[3]=f2bf(f0.w);
        ux.s[4]=f2bf(f1.x); ux.s[5]=f2bf(f1.y); ux.s[6]=f2bf(f1.z); ux.s[7]=f2bf(f1.w);
        uc.s[0]=f2bf(g0.x); uc.s[1]=f2bf(g0.y); uc.s[2]=f2bf(g0.z); uc.s[3]=f2bf(g0.w);
        uc.s[4]=f2bf(g1.x); uc.s[5]=f2bf(g1.y); uc.s[6]=f2bf(g1.z); uc.s[7]=f2bf(g1.w);
        *(int4*)(xs + sidx) = ux.v;
        *(int4*)(cs + sidx) = uc.v;
        __syncthreads();
        bf16x8 a = *(const bf16x8*)(xs + aidx);
        #pragma unroll
        for (int bt = 0; bt < 4; ++bt) {
            const int brow = 16 * bt + lr;
            bf16x8 b = *(const bf16x8*)(cs + brow * 32 + ((lg ^ ((brow >> 1) & 3)) * 8));
            acc[bt] = __builtin_amdgcn_mfma_f32_16x16x32_bf16(a, b, acc[bt], 0, 0, 0);
        }
    }
    const float sigma = sigp[0];
    const float* x2 = norms;
    const float* c2 = norms + NROWS;
    const int rbase = m0 + 16 * wave + lg * 4;
    float x2v[4];
    #pragma unroll
    for (int r = 0; r < 4; ++r) x2v[r] = x2[rbase + r];
    float rs[4] = {0.f, 0.f, 0.f, 0.f};
    #pragma unroll
    for (int bt = 0; bt < 4; ++bt) {
        const int col = n0 + 16 * bt + lr;
        const float c2v = c2[col];
        const float wvv = w[col];
        #pragma unroll
        for (int r = 0; r < 4; ++r) {
            float d2 = x2v[r] + c2v - 2.0f * acc[bt][r];
            d2 = fmaxf(d2, 0.0f);
            rs[r] += wvv * __expf(-sigma * d2);
        }
    }
    #pragma unroll
    for (int r = 0; r < 4; ++r) {
        rs[r] += __shfl_xor(rs[r], 1);
        rs[r] += __shfl_xor(rs[r], 2);
        rs[r] += __shfl_xor(rs[r], 4);
        rs[r] += __shfl_xor(rs[r], 8);
    }
    if (lr == 0) {
        #pragma unroll
        for (int r = 0; r < 4; ++r) atomicAdd(&out[rbase + r], rs[r]);
    }
}

extern "C" void kernel_launch(void* const* d_in, const int* in_sizes, int n_in,
                              void* d_out, int out_size, void* d_ws, size_t ws_size,
                              hipStream_t stream) {
    const float* x    = (const float*)d_in[0];
    const float* cent = (const float*)d_in[1];
    const float* w    = (const float*)d_in[2];
    const float* sig  = (const float*)d_in[3];
    float* out = (float*)d_out;

    const size_t norms_elems = NROWS + NCENT;              // 12288 floats
    const size_t xbf_off  = norms_elems * sizeof(float);   // 48 KB
    const size_t cbf_off  = xbf_off + (size_t)NROWS * DIM * sizeof(unsigned short);
    const size_t ws_need  = cbf_off + (size_t)NCENT * DIM * sizeof(unsigned short);

    if (ws_size >= ws_need) {
        float* norms = (float*)d_ws;
        unsigned short* xbf = (unsigned short*)((char*)d_ws + xbf_off);
        unsigned short* cbf = (unsigned short*)((char*)d_ws + cbf_off);
        prep_kernel<<<(NROWS + NCENT) / 16, 256, 0, stream>>>(x, cent, norms, xbf, cbf, out);
        rbf_mfma<<<dim3(NCENT / 128, NROWS / 128), 256, 0, stream>>>(xbf, cbf, w, sig, norms, out);
    } else {
        float* norms = (float*)d_ws;
        hipMemsetAsync(d_out, 0, (size_t)out_size * sizeof(float), stream);
        norms_kernel<<<(NROWS + NCENT) / 4, 256, 0, stream>>>(x, cent, norms);
        rbf_kernel<<<dim3(NCENT / 64, NROWS / 64), 256, 0, stream>>>(x, cent, w, sig, norms, out);
    }
}